// Round 5
// baseline (350.508 us; speedup 1.0000x reference)
//
#include <hip/hip_runtime.h>

#define C_DIM   128
#define O_MAX   10
#define BN_EPS  1e-5f
#define SLOPE   0.2f

typedef short s8v  __attribute__((ext_vector_type(8)));   // 8 bf16 (4 VGPRs)
typedef float f4v  __attribute__((ext_vector_type(4)));   // MFMA accumulator
#define MFMA(a,b,c) __builtin_amdgcn_mfma_f32_16x16x32_bf16(a,b,c,0,0,0)

__device__ inline unsigned short f2bf(float f) {          // RNE fp32->bf16
    unsigned u = __float_as_uint(f);
    unsigned r = u + 0x7FFFu + ((u >> 16) & 1u);
    return (unsigned short)(r >> 16);
}

// ---------------------------------------------------------------------------
// prep: w1n[n=(kk,oc)][c] bf16 ; w2b[oc][tap*64+c] bf16 (pad 584) ;
// w3b[oc][tap*32+c] bf16 ; zero BN sums.
// ---------------------------------------------------------------------------
#define N_W1N  73728
#define N_W2B  18688       /* 32*584 */
#define N_W3B  4608        /* 16*288 */
__global__ __launch_bounds__(256) void prep(
    const float* __restrict__ w1, const float* __restrict__ w2,
    const float* __restrict__ w3,
    short* __restrict__ w1n, short* __restrict__ w2b, short* __restrict__ w3b,
    float* __restrict__ sums)
{
    int i = blockIdx.x * 256 + threadIdx.x;
    if (i < N_W1N) {                       // w1n[n][c] = w1[oc][c][kk], n=kk*64+oc
        int n = i >> 7, c = i & 127;
        int kk = n >> 6, oc = n & 63;
        w1n[i] = f2bf(w1[oc * 1152 + c * 9 + kk]);
        return;
    }
    i -= N_W1N;
    if (i < N_W2B) {                       // w2b[oc][k2], k2 = tap*64+c
        int oc = i / 584, k2 = i % 584;
        int tap = k2 >> 6, c = k2 & 63;
        w2b[i] = (k2 < 576) ? f2bf(w2[oc * 576 + c * 9 + tap]) : (short)0;
        return;
    }
    i -= N_W2B;
    if (i < N_W3B) {                       // w3b[oc][k2], k2 = tap*32+c
        int oc = i >> 8, k2 = i & 255;     // careful: 288 not pow2 -> use div
        oc = i / 288; k2 = i - oc * 288;
        int tap = k2 >> 5, c = k2 & 31;
        w3b[i] = f2bf(w3[oc * 288 + c * 9 + tap]);
        return;
    }
    i -= N_W3B;
    if (i < 96) sums[i] = 0.f;
}

// ---------------------------------------------------------------------------
// stage1 (per-b block, 256 thr, 32000 B LDS -> 5 blocks/CU):
//   P0: LBF bf16 cast, AT2 tail zero, theta      | B
//   P1: fused A-GEMM MFMA -> AT2 scatter ; covpT computed DIRECTLY from theta | B
//   P2: conv1 MFMA (K=96)                        | B
//   P3: lrelu -> H1T (padded 10x10, stride 66)   | B
//   P4: im2col -> H2C                            | B
//   P5: conv2 MFMA (K split 2x288) + SCR reduce + BN2 sums via global atomics
// LDS: CPT 0..13312 | AT2 13312..26624 | LBF 26624..30720 | TH 30720..30960
// overlays: H1T 0..13200 (P3+) | H2C 13312..32000 (P4+) | SCR 0..2048 (P5)
// ---------------------------------------------------------------------------
__global__ __launch_bounds__(256) void stage1(
    const float* __restrict__ labels,   // (B,10,128) fp32
    const float* __restrict__ theta,
    const short* __restrict__ w1n,      // (576,128) bf16, n=kk*64+oc
    const short* __restrict__ w2b,      // (32,584) bf16
    const int*   __restrict__ maxobj_p,
    float* __restrict__ h2pre,          // (B,32,4,4)
    float* __restrict__ bn2s, float* __restrict__ bn2s2)
{
    __shared__ __align__(16) unsigned char smem[32000];
    short* CPT  = (short*)(smem);
    short* AT2  = (short*)(smem + 13312);
    short* LBF  = (short*)(smem + 26624);
    float* TH   = (float*)(smem + 30720);
    short* H1T  = (short*)(smem);
    short* H2C  = (short*)(smem + 13312);
    float* SCR  = (float*)(smem);

    const int b = blockIdx.x, t = threadIdx.x;
    const int w = t >> 6, l = t & 63, lm = l & 15, lq = l >> 4;
    const int nobj = min(maxobj_p[0], O_MAX);

    // ---- P0: LBF rows 0-9 from labels (rows 10-15 garbage -> discarded C rows),
    //          AT2 tail zero (k in [90,104)), theta
    for (int i = t; i < 320; i += 256) {             // 10 rows x 128 c / 4
        float4 v = *(const float4*)&labels[(size_t)b * 1280 + i * 4];
        unsigned lo = f2bf(v.x) | ((unsigned)f2bf(v.y) << 16);
        unsigned hi = f2bf(v.z) | ((unsigned)f2bf(v.w) << 16);
        *(uint2*)&LBF[i * 4] = make_uint2(lo, hi);
    }
    for (int i = t; i < 448; i += 256) {             // 64 oc x 7 u32 tail
        const int oc = i / 7, j = i - oc * 7;
        ((unsigned*)AT2)[oc * 52 + 45 + j] = 0u;
    }
    if (t < 60) TH[t] = theta[b * 60 + t];
    __syncthreads();

    // ---- P1a: fused A-GEMM.  wave w owns n in [w*144, w*144+144).
    {
        const int n00 = w * 144;
        s8v afr[4];
        #pragma unroll
        for (int ks = 0; ks < 4; ++ks)
            afr[ks] = *(const s8v*)&LBF[lm * 128 + lq * 8 + ks * 32];
        #pragma unroll
        for (int nt = 0; nt < 9; ++nt) {
            const int n = n00 + nt * 16 + lm;
            const short* brow = w1n + (size_t)n * 128 + lq * 8;
            f4v acc = (f4v){0.f, 0.f, 0.f, 0.f};
            #pragma unroll
            for (int ks = 0; ks < 4; ++ks) {
                s8v bb = *(const s8v*)(brow + ks * 32);
                acc = MFMA(afr[ks], bb, acc);
            }
            const int kk = n >> 6, oc = n & 63;
            #pragma unroll
            for (int r = 0; r < 4; ++r) {
                const int m = lq * 4 + r;
                if (m < 10)
                    AT2[oc * 104 + m * 9 + kk] = (short)f2bf(acc[r]);
            }
        }
    }
    // ---- P1b: covpT[p][k] computed directly (no COVf intermediate).
    for (int i = t; i < 6144; i += 256) {            // 96 k x 64 p
        const int k = i >> 6, p = i & 63;
        float val = 0.f;
        if (k < 90) {
            const int o  = (k * 456) >> 12;          // k/9
            const int kk = k - 9 * o;
            const int ky = (kk * 11) >> 5, kx = kk - 3 * ky;
            const int y = p >> 3, x = p & 7;
            const int py = 2 * y + ky - 1, px = 2 * x + kx - 1;
            if (o < nobj && (unsigned)py < 16u && (unsigned)px < 16u) {
                const float X = (2.f * px + 1.f) / 16.f - 1.f;
                const float Y = (2.f * py + 1.f) / 16.f - 1.f;
                const float* tt = &TH[o * 6];
                const float gx = tt[0] * X + tt[1] * Y + tt[2];
                const float gy = tt[3] * X + tt[4] * Y + tt[5];
                float ix = (gx + 1.f) * 8.f - 0.5f;
                float x0 = floorf(ix), fx = ix - x0;
                float inx0 = (x0 >= 0.f  && x0 <= 15.f) ? 1.f : 0.f;
                float inx1 = (x0 >= -1.f && x0 <= 14.f) ? 1.f : 0.f;
                float cx = (1.f - fx) * inx0 + fx * inx1;
                float iy = (gy + 1.f) * 8.f - 0.5f;
                float y0 = floorf(iy), fy = iy - y0;
                float iny0 = (y0 >= 0.f  && y0 <= 15.f) ? 1.f : 0.f;
                float iny1 = (y0 >= -1.f && y0 <= 14.f) ? 1.f : 0.f;
                float cy = (1.f - fy) * iny0 + fy * iny1;
                val = cx * cy;
            }
        }
        CPT[p * 104 + k] = (short)f2bf(val);
    }
    __syncthreads();

    // ---- P2: conv1 MFMA.  wave w -> oc tile [16w,16w+16); K=96
    f4v c1[4];
    #pragma unroll
    for (int nt = 0; nt < 4; ++nt) c1[nt] = (f4v){0.f, 0.f, 0.f, 0.f};
    {
        const short* at = AT2 + (16 * w + lm) * 104 + lq * 8;
        const short* cp = CPT + lm * 104 + lq * 8;
        #pragma unroll
        for (int ks = 0; ks < 3; ++ks) {
            s8v a = *(const s8v*)(at + ks * 32);
            #pragma unroll
            for (int nt = 0; nt < 4; ++nt) {
                s8v bb = *(const s8v*)(cp + nt * 1664 + ks * 32);
                c1[nt] = MFMA(a, bb, c1[nt]);
            }
        }
    }
    __syncthreads();   // CPT/AT2 reads done before H1T overlay writes

    // ---- P3: zero H1T border rows, write lrelu(bf16) interior
    for (int i = t; i < 1188; i += 256) {           // 36 border rows x 33 u32
        const int j = i / 33, col = i - 33 * j;
        int r;
        if (j < 10) r = j;
        else if (j < 20) r = 90 + (j - 10);
        else { int jj = j - 20; r = 10 + (jj >> 1) * 10 + ((jj & 1) ? 9 : 0); }
        ((unsigned*)H1T)[r * 33 + col] = 0u;
    }
    #pragma unroll
    for (int nt = 0; nt < 4; ++nt) {
        const int p = nt * 16 + lm, y = p >> 3, x = p & 7;
        const int pix = (y + 1) * 10 + (x + 1);
        #pragma unroll
        for (int r = 0; r < 4; ++r) {
            const int oc = 16 * w + lq * 4 + r;
            float v = c1[nt][r];
            v = (v >= 0.f) ? v : SLOPE * v;
            H1T[pix * 66 + oc] = (short)f2bf(v);
        }
    }
    __syncthreads();

    // ---- P4: im2col pairs -> h2colT[p2][k2=tap*64+c] (stride 584)
    for (int i = t; i < 4608; i += 256) {
        const int p2 = i & 15, kp = i >> 4;         // kp = tap*32 + c2
        const int c2 = kp & 31, tap = kp >> 5;
        const int ky = (tap * 11) >> 5, kx = tap - 3 * ky;
        const int y2 = p2 >> 2, x2 = p2 & 3;
        const int pix = (2 * y2 + ky) * 10 + (2 * x2 + kx);
        const unsigned v = *(const unsigned*)&H1T[pix * 66 + 2 * c2];
        *(unsigned*)&H2C[p2 * 584 + tap * 64 + 2 * c2] = v;
    }
    __syncthreads();

    // ---- P5: conv2 MFMA. wave: mi = w&1 (oc tile), kh = w>>1 (K half)
    {
        const int mi = w & 1, kh = w >> 1;
        f4v c2 = (f4v){0.f, 0.f, 0.f, 0.f};
        const short* wrow = w2b + (mi * 16 + lm) * 584 + kh * 288 + lq * 8;
        const short* hrow = H2C + lm * 584 + kh * 288 + lq * 8;
        #pragma unroll
        for (int ks = 0; ks < 9; ++ks) {
            s8v a  = *(const s8v*)(wrow + ks * 32);
            s8v bb = *(const s8v*)(hrow + ks * 32);
            c2 = MFMA(a, bb, c2);
        }
        if (kh == 1) *(f4v*)&SCR[(mi * 64 + l) * 4] = c2;
        __syncthreads();
        if (kh == 0) {
            f4v oth = *(const f4v*)&SCR[(mi * 64 + l) * 4];
            #pragma unroll
            for (int r = 0; r < 4; ++r) {
                const int oc = mi * 16 + lq * 4 + r;
                float v = c2[r] + oth[r];
                h2pre[(size_t)b * 512 + oc * 16 + lm] = v;
                float s1 = v, s2 = v * v;
                #pragma unroll
                for (int m = 1; m < 16; m <<= 1) {
                    s1 += __shfl_xor(s1, m, 16);
                    s2 += __shfl_xor(s2, m, 16);
                }
                if (lm == 0) {
                    atomicAdd(&bn2s[oc],  s1);
                    atomicAdd(&bn2s2[oc], s2);
                }
            }
        }
    }
}

// ---------------------------------------------------------------------------
// stage2 (4 b per block): BN2+lrelu -> s_pad ; im2col -> h3colT bf16 ;
// conv3 as one 16x16x288 MFMA GEMM on wave 0 ; BN3 sums via shfl+atomics.
// ---------------------------------------------------------------------------
__global__ __launch_bounds__(256) void stage2(
    const float* __restrict__ h2pre,
    const float* __restrict__ gamma2, const float* __restrict__ beta2,
    const short* __restrict__ w3b,    // (16,288) bf16, k2=tap*32+c
    const float* __restrict__ bn2s, const float* __restrict__ bn2s2,
    float* __restrict__ h3pre,
    float* __restrict__ bn3s, float* __restrict__ bn3s2, int B)
{
    const int b0 = blockIdx.x * 4, t = threadIdx.x;
    const int w = t >> 6, l = t & 63, lm = l & 15, lq = l >> 4;
    __shared__ float s_ss[64];                    // scale[32] | shift[32]
    __shared__ float s_pad[4 * 32 * 36];          // padded 6x6 per (b,c)
    __shared__ __align__(16) short h3c[16 * 296]; // [n=(lb,p)][k2], stride 296

    if (t < 32) {
        const float n = (float)B * 16.f;
        const float mean = bn2s[t] / n;
        const float var  = bn2s2[t] / n - mean * mean;
        const float sc   = gamma2[t] * rsqrtf(var + BN_EPS);
        s_ss[t] = sc;
        s_ss[32 + t] = beta2[t] - mean * sc;
    }
    for (int i = t; i < 4608; i += 256) s_pad[i] = 0.f;
    __syncthreads();

    for (int i = t; i < 2048; i += 256) {
        const int lb = i >> 9, r = i & 511;
        const int c = r >> 4, p = r & 15, y = p >> 2, x = p & 3;
        const float v = h2pre[(size_t)b0 * 512 + i] * s_ss[c] + s_ss[32 + c];
        s_pad[lb * 1152 + c * 36 + (y + 1) * 6 + (x + 1)] = (v >= 0.f) ? v : SLOPE * v;
    }
    __syncthreads();

    // im2col: h3c[n][k2=tap*32+c], n = lb*4 + p
    for (int i = t; i < 4608; i += 256) {
        const int n = i & 15, k2 = i >> 4;
        const int c = k2 & 31, tap = k2 >> 5;
        const int ky = (tap * 11) >> 5, kx = tap - 3 * ky;
        const int lb = n >> 2, p = n & 3, y = p >> 1, x = p & 1;
        const float v = s_pad[lb * 1152 + c * 36 + (2 * y + ky) * 6 + (2 * x + kx)];
        h3c[n * 296 + k2] = (short)f2bf(v);
    }
    __syncthreads();

    if (w == 0) {
        f4v acc = (f4v){0.f, 0.f, 0.f, 0.f};
        const short* wr = w3b + lm * 288 + lq * 8;
        const short* hr = h3c + lm * 296 + lq * 8;
        #pragma unroll
        for (int ks = 0; ks < 9; ++ks) {
            s8v a  = *(const s8v*)(wr + ks * 32);
            s8v bb = *(const s8v*)(hr + ks * 32);
            acc = MFMA(a, bb, acc);
        }
        const int lb = lm >> 2, p = lm & 3;
        #pragma unroll
        for (int r = 0; r < 4; ++r) {
            const int oc = lq * 4 + r;
            const float v = acc[r];
            h3pre[(size_t)(b0 + lb) * 64 + oc * 4 + p] = v;
            float s1 = v, s2 = v * v;
            #pragma unroll
            for (int m = 1; m < 16; m <<= 1) {
                s1 += __shfl_xor(s1, m, 16);
                s2 += __shfl_xor(s2, m, 16);
            }
            if (lm == 0) {
                atomicAdd(&bn3s[oc],  s1);
                atomicAdd(&bn3s2[oc], s2);
            }
        }
    }
}

// ---------------------------------------------------------------------------
// stage3: BN3 + lrelu -> out (B,64)
// ---------------------------------------------------------------------------
__global__ __launch_bounds__(256) void stage3(
    const float* __restrict__ h3pre,
    const float* __restrict__ gamma3, const float* __restrict__ beta3,
    const float* __restrict__ bn3s, const float* __restrict__ bn3s2,
    float* __restrict__ out, int total, int B)
{
    __shared__ float s_scale[16], s_shift[16];
    if (threadIdx.x < 16) {
        const int c = threadIdx.x;
        const float n = (float)B * 4.f;
        const float mean = bn3s[c] / n;
        const float var  = bn3s2[c] / n - mean * mean;
        const float sc   = gamma3[c] * rsqrtf(var + BN_EPS);
        s_scale[c] = sc;
        s_shift[c] = beta3[c] - mean * sc;
    }
    __syncthreads();
    const int idx = blockIdx.x * 256 + threadIdx.x;
    if (idx < total) {
        const int c = (idx & 63) >> 2;
        const float v = h3pre[idx] * s_scale[c] + s_shift[c];
        out[idx] = (v >= 0.f) ? v : SLOPE * v;
    }
}

extern "C" void kernel_launch(void* const* d_in, const int* in_sizes, int n_in,
                              void* d_out, int out_size, void* d_ws, size_t ws_size,
                              hipStream_t stream)
{
    const float* labels = (const float*)d_in[0];
    const float* theta  = (const float*)d_in[1];
    const float* w1     = (const float*)d_in[2];
    const float* w2     = (const float*)d_in[3];
    const float* gamma2 = (const float*)d_in[4];
    const float* beta2  = (const float*)d_in[5];
    const float* w3     = (const float*)d_in[6];
    const float* gamma3 = (const float*)d_in[7];
    const float* beta3  = (const float*)d_in[8];
    const int*   maxobj = (const int*)d_in[9];

    const int B = in_sizes[0] / (O_MAX * C_DIM);   // 2048

    unsigned char* ws = (unsigned char*)d_ws;
    float* h2pre = (float*)ws;                                  // B*512 f32
    float* h3pre = h2pre + (size_t)B * 512;                     // B*64
    float* sums  = h3pre + (size_t)B * 64;                      // 96
    short* w1n   = (short*)(sums + 96);                         // 73728 sh
    short* w2b   = w1n + N_W1N;                                 // 18688 sh
    short* w3b   = w2b + N_W2B;                                 // 4608 sh
    float* bn2s  = sums;
    float* bn2s2 = sums + 32;
    float* bn3s  = sums + 64;
    float* bn3s2 = sums + 80;

    const int prep_total = N_W1N + N_W2B + N_W3B + 96;
    prep<<<(prep_total + 255) / 256, 256, 0, stream>>>(w1, w2, w3,
                                                       w1n, w2b, w3b, sums);
    stage1<<<B, 256, 0, stream>>>(labels, theta, w1n, w2b, maxobj,
                                  h2pre, bn2s, bn2s2);
    stage2<<<B / 4, 256, 0, stream>>>(h2pre, gamma2, beta2, w3b, bn2s, bn2s2,
                                      h3pre, bn3s, bn3s2, B);
    const int total = B * 64;
    stage3<<<(total + 255) / 256, 256, 0, stream>>>(h3pre, gamma3, beta3,
                                                    bn3s, bn3s2, (float*)d_out,
                                                    total, B);
}

// Round 6
// 204.814 us; speedup vs baseline: 1.7113x; 1.7113x over previous
//
#include <hip/hip_runtime.h>

#define C_DIM   128
#define O_MAX   10
#define BN_EPS  1e-5f
#define SLOPE   0.2f

typedef short s8v  __attribute__((ext_vector_type(8)));   // 8 bf16 (4 VGPRs)
typedef float f4v  __attribute__((ext_vector_type(4)));   // MFMA accumulator
#define MFMA(a,b,c) __builtin_amdgcn_mfma_f32_16x16x32_bf16(a,b,c,0,0,0)

__device__ inline unsigned short f2bf(float f) {          // RNE fp32->bf16
    unsigned u = __float_as_uint(f);
    unsigned r = u + 0x7FFFu + ((u >> 16) & 1u);
    return (unsigned short)(r >> 16);
}

// ---------------------------------------------------------------------------
// prep: w1n[n=(kk,oc)][c] bf16 ; w2b[oc][tap*64+c] bf16 (pad 584) ;
// w3b[oc][tap*32+c] bf16 ; zero BN sums.
// ---------------------------------------------------------------------------
#define N_W1N  73728
#define N_W2B  18688       /* 32*584 */
#define N_W3B  4608        /* 16*288 */
__global__ __launch_bounds__(256) void prep(
    const float* __restrict__ w1, const float* __restrict__ w2,
    const float* __restrict__ w3,
    short* __restrict__ w1n, short* __restrict__ w2b, short* __restrict__ w3b,
    float* __restrict__ sums)
{
    int i = blockIdx.x * 256 + threadIdx.x;
    if (i < N_W1N) {                       // w1n[n][c] = w1[oc][c][kk], n=kk*64+oc
        int n = i >> 7, c = i & 127;
        int kk = n >> 6, oc = n & 63;
        w1n[i] = f2bf(w1[oc * 1152 + c * 9 + kk]);
        return;
    }
    i -= N_W1N;
    if (i < N_W2B) {                       // w2b[oc][k2], k2 = tap*64+c
        int oc = i / 584, k2 = i % 584;
        int tap = k2 >> 6, c = k2 & 63;
        w2b[i] = (k2 < 576) ? f2bf(w2[oc * 576 + c * 9 + tap]) : (short)0;
        return;
    }
    i -= N_W2B;
    if (i < N_W3B) {                       // w3b[oc][k2], k2 = tap*32+c
        int oc = i / 288, k2 = i - oc * 288;
        int tap = k2 >> 5, c = k2 & 31;
        w3b[i] = f2bf(w3[oc * 288 + c * 9 + tap]);
        return;
    }
    i -= N_W3B;
    if (i < 96) sums[i] = 0.f;
}

// ---------------------------------------------------------------------------
// stage1: EXACT R4 structure (96.5 us verified; 68 VGPR, 46.6 KB LDS).
// R5's LDS-diet variant regressed 2.5x (ILP collapse at 44 VGPR) - reverted.
// ---------------------------------------------------------------------------
__global__ __launch_bounds__(256) void stage1(
    const float* __restrict__ labels,   // (B,10,128) fp32
    const float* __restrict__ theta,
    const short* __restrict__ w1n,      // (576,128) bf16, n=kk*64+oc
    const short* __restrict__ w2b,      // (32,584) bf16
    const int*   __restrict__ maxobj_p,
    float* __restrict__ h2pre,          // (B,32,4,4)
    float* __restrict__ bn2s, float* __restrict__ bn2s2)
{
    __shared__ __align__(16) unsigned char smem[46224];
    float* COVf = (float*)(smem);
    short* CPT  = (short*)(smem + 12960);
    short* AT2  = (short*)(smem + 26272);
    short* LBF  = (short*)(smem + 39584);
    short* H1T  = (short*)(smem);
    short* H2C  = (short*)(smem + 13216);
    float* SCR  = (float*)(smem + 43680);
    float* TH   = (float*)(smem + 45728);
    float* CS   = (float*)(smem + 45968);
    float* CS2  = (float*)(smem + 46096);

    const int b = blockIdx.x, t = threadIdx.x;
    const int w = t >> 6, l = t & 63, lm = l & 15, lq = l >> 4;
    const int nobj = min(maxobj_p[0], O_MAX);

    // ---- phase 0: zero COVf/CPT/AT2, LBF rows 0-9 from labels + 10-15 zero
    for (int i = t; i < 3240; i += 256) COVf[i] = 0.f;
    for (int i = t; i < 3328; i += 256) ((unsigned*)CPT)[i] = 0u;
    for (int i = t; i < 3328; i += 256) ((unsigned*)AT2)[i] = 0u;
    for (int i = t; i < 320; i += 256) {             // 10 rows x 128 c / 4
        float4 v = *(const float4*)&labels[(size_t)b * 1280 + i * 4];
        unsigned lo = f2bf(v.x) | ((unsigned)f2bf(v.y) << 16);
        unsigned hi = f2bf(v.z) | ((unsigned)f2bf(v.w) << 16);
        *(uint2*)&LBF[i * 4] = make_uint2(lo, hi);
    }
    for (int i = t; i < 384; i += 256) ((unsigned*)LBF)[640 + i] = 0u;
    if (t < 60) TH[t] = theta[b * 60 + t];
    __syncthreads();

    // ---- phase 1a: coverage (interior of padded 18x18) -> COVf
    for (int i = t; i < 2560; i += 256) {
        const int o = i >> 8;
        if (o >= nobj) continue;
        const int p = i & 255, y = p >> 4, x = p & 15;
        const float X = (2.f * x + 1.f) / 16.f - 1.f;
        const float Y = (2.f * y + 1.f) / 16.f - 1.f;
        const float* tt = &TH[o * 6];
        const float gx = tt[0] * X + tt[1] * Y + tt[2];
        const float gy = tt[3] * X + tt[4] * Y + tt[5];
        float ix = (gx + 1.f) * 8.f - 0.5f;
        float x0 = floorf(ix); float fx = ix - x0;
        float inx0 = (x0 >= 0.f  && x0 <= 15.f) ? 1.f : 0.f;
        float inx1 = (x0 >= -1.f && x0 <= 14.f) ? 1.f : 0.f;
        float cx = (1.f - fx) * inx0 + fx * inx1;
        float iy = (gy + 1.f) * 8.f - 0.5f;
        float y0 = floorf(iy); float fy = iy - y0;
        float iny0 = (y0 >= 0.f  && y0 <= 15.f) ? 1.f : 0.f;
        float iny1 = (y0 >= -1.f && y0 <= 14.f) ? 1.f : 0.f;
        float cy = (1.f - fy) * iny0 + fy * iny1;
        COVf[o * 324 + (y + 1) * 18 + (x + 1)] = cx * cy;
    }

    // ---- phase 1b: fused A-GEMM.  wave w owns n in [w*144, w*144+144).
    {
        const int n00 = w * 144;
        s8v afr[4];
        #pragma unroll
        for (int ks = 0; ks < 4; ++ks)
            afr[ks] = *(const s8v*)&LBF[lm * 128 + lq * 8 + ks * 32];
        #pragma unroll
        for (int nt = 0; nt < 9; ++nt) {
            const int n = n00 + nt * 16 + lm;
            const short* brow = w1n + (size_t)n * 128 + lq * 8;
            f4v acc = (f4v){0.f, 0.f, 0.f, 0.f};
            #pragma unroll
            for (int ks = 0; ks < 4; ++ks) {
                s8v bb = *(const s8v*)(brow + ks * 32);
                acc = MFMA(afr[ks], bb, acc);
            }
            const int kk = n >> 6, oc = n & 63;
            #pragma unroll
            for (int r = 0; r < 4; ++r) {
                const int m = lq * 4 + r;
                if (m < 10)
                    AT2[oc * 104 + m * 9 + kk] = (short)f2bf(acc[r]);
            }
        }
    }
    __syncthreads();

    // ---- phase 2: covpT[p][k] bf16 (k = o*9+kk); zeros gate k>=90, o>=nobj
    for (int i = t; i < 5760; i += 256) {
        const int k = i >> 6, p = i & 63;
        const int o = k / 9, kk = k - 9 * o;
        if (o < nobj) {
            const int ky = kk / 3, kx = kk - 3 * ky;
            const int y = p >> 3, x = p & 7;
            CPT[p * 104 + k] = (short)f2bf(COVf[o * 324 + (2 * y + ky) * 18 + (2 * x + kx)]);
        }
    }
    __syncthreads();

    // ---- phase 3: conv1 MFMA.  wave w -> oc tile [16w,16w+16); K=96
    f4v c1[4];
    #pragma unroll
    for (int nt = 0; nt < 4; ++nt) c1[nt] = (f4v){0.f, 0.f, 0.f, 0.f};
    {
        const short* at = AT2 + (16 * w + lm) * 104 + lq * 8;
        const short* cp = CPT + lm * 104 + lq * 8;
        #pragma unroll
        for (int ks = 0; ks < 3; ++ks) {
            s8v a = *(const s8v*)(at + ks * 32);
            #pragma unroll
            for (int nt = 0; nt < 4; ++nt) {
                s8v bb = *(const s8v*)(cp + nt * 1664 + ks * 32);
                c1[nt] = MFMA(a, bb, c1[nt]);
            }
        }
    }
    __syncthreads();   // CPT/AT2 reads done before H1T overlay writes

    // conv1 epilogue: zero H1T border rows, write lrelu(bf16) interior
    for (int i = t; i < 1188; i += 256) {           // 36 border rows x 33 u32
        const int j = i / 33, col = i - 33 * j;
        int r;
        if (j < 10) r = j;
        else if (j < 20) r = 90 + (j - 10);
        else { int jj = j - 20; r = 10 + (jj >> 1) * 10 + ((jj & 1) ? 9 : 0); }
        ((unsigned*)H1T)[r * 33 + col] = 0u;
    }
    #pragma unroll
    for (int nt = 0; nt < 4; ++nt) {
        const int p = nt * 16 + lm, y = p >> 3, x = p & 7;
        const int pix = (y + 1) * 10 + (x + 1);
        #pragma unroll
        for (int r = 0; r < 4; ++r) {
            const int oc = 16 * w + lq * 4 + r;
            float v = c1[nt][r];
            v = (v >= 0.f) ? v : SLOPE * v;
            H1T[pix * 66 + oc] = (short)f2bf(v);
        }
    }
    __syncthreads();

    // ---- phase 4: im2col pairs -> h2colT[p2][k2=tap*64+c] (stride 584)
    for (int i = t; i < 4608; i += 256) {
        const int p2 = i & 15, kp = i >> 4;         // kp = tap*32 + c2
        const int c2 = kp & 31, tap = kp >> 5;
        const int ky = (tap * 11) >> 5, kx = tap - 3 * ky;
        const int y2 = p2 >> 2, x2 = p2 & 3;
        const int pix = (2 * y2 + ky) * 10 + (2 * x2 + kx);
        const unsigned v = *(const unsigned*)&H1T[pix * 66 + 2 * c2];
        *(unsigned*)&H2C[p2 * 584 + tap * 64 + 2 * c2] = v;
    }
    __syncthreads();

    // ---- phase 5: conv2 MFMA. wave: mi = w&1 (oc tile), kh = w>>1 (K half)
    {
        const int mi = w & 1, kh = w >> 1;
        f4v c2 = (f4v){0.f, 0.f, 0.f, 0.f};
        const short* wrow = w2b + (mi * 16 + lm) * 584 + kh * 288 + lq * 8;
        const short* hrow = H2C + lm * 584 + kh * 288 + lq * 8;
        #pragma unroll
        for (int ks = 0; ks < 9; ++ks) {
            s8v a  = *(const s8v*)(wrow + ks * 32);
            s8v bb = *(const s8v*)(hrow + ks * 32);
            c2 = MFMA(a, bb, c2);
        }
        if (kh == 1) *(f4v*)&SCR[(mi * 64 + l) * 4] = c2;
        __syncthreads();
        if (kh == 0) {
            f4v oth = *(const f4v*)&SCR[(mi * 64 + l) * 4];
            #pragma unroll
            for (int r = 0; r < 4; ++r) {
                const int oc = mi * 16 + lq * 4 + r;
                float v = c2[r] + oth[r];
                h2pre[(size_t)b * 512 + oc * 16 + lm] = v;
                float s1 = v, s2 = v * v;
                #pragma unroll
                for (int m = 1; m < 16; m <<= 1) {
                    s1 += __shfl_xor(s1, m, 16);
                    s2 += __shfl_xor(s2, m, 16);
                }
                if (lm == 0) { CS[oc] = s1; CS2[oc] = s2; }
            }
        }
    }
    __syncthreads();
    if (t < 32) {
        atomicAdd(&bn2s[t],  CS[t]);
        atomicAdd(&bn2s2[t], CS2[t]);
    }
}

// ---------------------------------------------------------------------------
// stage2 (8 b per block, 256 blocks): BN2+lrelu -> s_h2a bf16 ; im2col gather
// -> h3c bf16 ; conv3 as two 16x16x288 MFMA tiles (waves 0,1) ; BN3 sums.
// LDS ~27.4 KB -> 5 blocks/CU.
// ---------------------------------------------------------------------------
__global__ __launch_bounds__(256) void stage2(
    const float* __restrict__ h2pre,
    const float* __restrict__ gamma2, const float* __restrict__ beta2,
    const short* __restrict__ w3b,    // (16,288) bf16, k2=tap*32+c
    const float* __restrict__ bn2s, const float* __restrict__ bn2s2,
    float* __restrict__ h3pre,        // (B,16,2,2)
    float* __restrict__ bn3s, float* __restrict__ bn3s2, int B)
{
    const int b0 = blockIdx.x * 8, t = threadIdx.x;
    const int w = t >> 6, l = t & 63, lm = l & 15, lq = l >> 4;
    __shared__ float s_ss[64];                      // scale[32] | shift[32]
    __shared__ short s_h2a[8 * 512];                // [lb][c][p] bf16, 8 KB
    __shared__ __align__(16) short h3c[32 * 296];   // [n=(lb,p)][k2], 18.9 KB

    if (t < 32) {
        const float n = (float)B * 16.f;
        const float mean = bn2s[t] / n;
        const float var  = bn2s2[t] / n - mean * mean;
        const float sc   = gamma2[t] * rsqrtf(var + BN_EPS);
        s_ss[t] = sc;
        s_ss[32 + t] = beta2[t] - mean * sc;
    }
    __syncthreads();

    // BN2 + lrelu -> s_h2a (bf16), coalesced global reads
    for (int i = t; i < 4096; i += 256) {
        const int c = (i >> 4) & 31;
        const float v = h2pre[(size_t)b0 * 512 + i] * s_ss[c] + s_ss[32 + c];
        s_h2a[i] = (short)f2bf((v >= 0.f) ? v : SLOPE * v);
    }
    __syncthreads();

    // im2col gather: h3c[n][k2], n = lb*4+p, k2 = tap*32+c
    for (int i = t; i < 9216; i += 256) {
        const int n = i & 31, k2 = i >> 5;
        const int c = k2 & 31, tap = k2 >> 5;
        const int ky = (tap * 11) >> 5, kx = tap - 3 * ky;
        const int lb = n >> 2, p = n & 3, y = p >> 1, x = p & 1;
        const int iy = 2 * y + ky - 1, ix = 2 * x + kx - 1;
        short v = 0;
        if ((unsigned)iy < 4u && (unsigned)ix < 4u)
            v = s_h2a[lb * 512 + c * 16 + iy * 4 + ix];
        h3c[n * 296 + k2] = v;
    }
    __syncthreads();

    if (w < 2) {            // wave w handles n rows [16w, 16w+16)
        f4v acc = (f4v){0.f, 0.f, 0.f, 0.f};
        const short* wr = w3b + lm * 288 + lq * 8;
        const short* hr = h3c + (w * 16 + lm) * 296 + lq * 8;
        #pragma unroll
        for (int ks = 0; ks < 9; ++ks) {
            s8v a  = *(const s8v*)(wr + ks * 32);
            s8v bb = *(const s8v*)(hr + ks * 32);
            acc = MFMA(a, bb, acc);
        }
        const int n = w * 16 + lm, lb = n >> 2, p = n & 3;
        #pragma unroll
        for (int r = 0; r < 4; ++r) {
            const int oc = lq * 4 + r;
            const float v = acc[r];
            h3pre[(size_t)(b0 + lb) * 64 + oc * 4 + p] = v;
            float s1 = v, s2 = v * v;
            #pragma unroll
            for (int m = 1; m < 16; m <<= 1) {
                s1 += __shfl_xor(s1, m, 16);
                s2 += __shfl_xor(s2, m, 16);
            }
            if (lm == 0) {
                atomicAdd(&bn3s[oc],  s1);
                atomicAdd(&bn3s2[oc], s2);
            }
        }
    }
}

// ---------------------------------------------------------------------------
// stage3: BN3 + lrelu -> out (B,64)
// ---------------------------------------------------------------------------
__global__ __launch_bounds__(256) void stage3(
    const float* __restrict__ h3pre,
    const float* __restrict__ gamma3, const float* __restrict__ beta3,
    const float* __restrict__ bn3s, const float* __restrict__ bn3s2,
    float* __restrict__ out, int total, int B)
{
    __shared__ float s_scale[16], s_shift[16];
    if (threadIdx.x < 16) {
        const int c = threadIdx.x;
        const float n = (float)B * 4.f;
        const float mean = bn3s[c] / n;
        const float var  = bn3s2[c] / n - mean * mean;
        const float sc   = gamma3[c] * rsqrtf(var + BN_EPS);
        s_scale[c] = sc;
        s_shift[c] = beta3[c] - mean * sc;
    }
    __syncthreads();
    const int idx = blockIdx.x * 256 + threadIdx.x;
    if (idx < total) {
        const int c = (idx & 63) >> 2;
        const float v = h3pre[idx] * s_scale[c] + s_shift[c];
        out[idx] = (v >= 0.f) ? v : SLOPE * v;
    }
}

extern "C" void kernel_launch(void* const* d_in, const int* in_sizes, int n_in,
                              void* d_out, int out_size, void* d_ws, size_t ws_size,
                              hipStream_t stream)
{
    const float* labels = (const float*)d_in[0];
    const float* theta  = (const float*)d_in[1];
    const float* w1     = (const float*)d_in[2];
    const float* w2     = (const float*)d_in[3];
    const float* gamma2 = (const float*)d_in[4];
    const float* beta2  = (const float*)d_in[5];
    const float* w3     = (const float*)d_in[6];
    const float* gamma3 = (const float*)d_in[7];
    const float* beta3  = (const float*)d_in[8];
    const int*   maxobj = (const int*)d_in[9];

    const int B = in_sizes[0] / (O_MAX * C_DIM);   // 2048

    unsigned char* ws = (unsigned char*)d_ws;
    float* h2pre = (float*)ws;                                  // B*512 f32
    float* h3pre = h2pre + (size_t)B * 512;                     // B*64
    float* sums  = h3pre + (size_t)B * 64;                      // 96
    short* w1n   = (short*)(sums + 96);                         // 73728 sh
    short* w2b   = w1n + N_W1N;                                 // 18688 sh
    short* w3b   = w2b + N_W2B;                                 // 4608 sh
    float* bn2s  = sums;
    float* bn2s2 = sums + 32;
    float* bn3s  = sums + 64;
    float* bn3s2 = sums + 80;

    const int prep_total = N_W1N + N_W2B + N_W3B + 96;
    prep<<<(prep_total + 255) / 256, 256, 0, stream>>>(w1, w2, w3,
                                                       w1n, w2b, w3b, sums);
    stage1<<<B, 256, 0, stream>>>(labels, theta, w1n, w2b, maxobj,
                                  h2pre, bn2s, bn2s2);
    stage2<<<B / 8, 256, 0, stream>>>(h2pre, gamma2, beta2, w3b, bn2s, bn2s2,
                                      h3pre, bn3s, bn3s2, B);
    const int total = B * 64;
    stage3<<<(total + 255) / 256, 256, 0, stream>>>(h3pre, gamma3, beta3,
                                                    bn3s, bn3s2, (float*)d_out,
                                                    total, B);
}

// Round 7
// 199.897 us; speedup vs baseline: 1.7534x; 1.0246x over previous
//
#include <hip/hip_runtime.h>

#define C_DIM   128
#define O_MAX   10
#define BN_EPS  1e-5f
#define SLOPE   0.2f

typedef short s8v  __attribute__((ext_vector_type(8)));   // 8 bf16 (4 VGPRs)
typedef float f4v  __attribute__((ext_vector_type(4)));   // MFMA accumulator
#define MFMA(a,b,c) __builtin_amdgcn_mfma_f32_16x16x32_bf16(a,b,c,0,0,0)

__device__ inline unsigned short f2bf(float f) {          // RNE fp32->bf16
    unsigned u = __float_as_uint(f);
    unsigned r = u + 0x7FFFu + ((u >> 16) & 1u);
    return (unsigned short)(r >> 16);
}

// ---------------------------------------------------------------------------
// prep: w1n[n=(kk,oc)][c] bf16 ; w2b[oc][tap*64+c] bf16 (pad 584) ;
// w3b[oc][tap*32+c] bf16 ; zero BN sums.   (identical to R6)
// ---------------------------------------------------------------------------
#define N_W1N  73728
#define N_W2B  18688       /* 32*584 */
#define N_W3B  4608        /* 16*288 */
__global__ __launch_bounds__(256) void prep(
    const float* __restrict__ w1, const float* __restrict__ w2,
    const float* __restrict__ w3,
    short* __restrict__ w1n, short* __restrict__ w2b, short* __restrict__ w3b,
    float* __restrict__ sums)
{
    int i = blockIdx.x * 256 + threadIdx.x;
    if (i < N_W1N) {                       // w1n[n][c] = w1[oc][c][kk], n=kk*64+oc
        int n = i >> 7, c = i & 127;
        int kk = n >> 6, oc = n & 63;
        w1n[i] = f2bf(w1[oc * 1152 + c * 9 + kk]);
        return;
    }
    i -= N_W1N;
    if (i < N_W2B) {                       // w2b[oc][k2], k2 = tap*64+c
        int oc = i / 584, k2 = i % 584;
        int tap = k2 >> 6, c = k2 & 63;
        w2b[i] = (k2 < 576) ? f2bf(w2[oc * 576 + c * 9 + tap]) : (short)0;
        return;
    }
    i -= N_W2B;
    if (i < N_W3B) {                       // w3b[oc][k2], k2 = tap*32+c
        int oc = i / 288, k2 = i - oc * 288;
        int tap = k2 >> 5, c = k2 & 31;
        w3b[i] = f2bf(w3[oc * 288 + c * 9 + tap]);
        return;
    }
    i -= N_W3B;
    if (i < 96) sums[i] = 0.f;
}

// ---------------------------------------------------------------------------
// stage1: R4 structure (96.5us verified), LDS-trimmed 46.6K -> 39.7K to reach
// 4 blocks/CU.  Compute phases byte-identical; only layout changes:
//   COVf: padded 18x18 -> unpadded stride-17 rows + bounds predicate at gather
//   CPT/AT2 row stride 104 -> 96 shorts (16B aligned, 2-way bank = free)
//   LBF: 10 real rows only (garbage-row MFMA reads feed discarded C rows)
//   dead pre-zero loops dropped (every COVf read slot written or predicated)
// LDS (bytes): COVf 0..10880 | CPT 10880..23168 | AT2 23168..35456 |
//   LBF 35456..38016 (+overread to 39552) | TH 38016 | CS 38256 | CS2 38384
// overlays: H1T 0..13200 (after conv1) | H2C 13312..32000 | SCR 32000..34048
// ---------------------------------------------------------------------------
__global__ __launch_bounds__(256) void stage1(
    const float* __restrict__ labels,   // (B,10,128) fp32
    const float* __restrict__ theta,
    const short* __restrict__ w1n,      // (576,128) bf16, n=kk*64+oc
    const short* __restrict__ w2b,      // (32,584) bf16
    const int*   __restrict__ maxobj_p,
    float* __restrict__ h2pre,          // (B,32,4,4)
    float* __restrict__ bn2s, float* __restrict__ bn2s2)
{
    __shared__ __align__(16) unsigned char smem[39680];
    float* COVf = (float*)(smem);                 // [o][y*17+x], stride 272/o
    short* CPT  = (short*)(smem + 10880);         // [p][96]
    short* AT2  = (short*)(smem + 23168);         // [oc][96]
    short* LBF  = (short*)(smem + 35456);         // [10][128]
    float* TH   = (float*)(smem + 38016);
    float* CS   = (float*)(smem + 38256);
    float* CS2  = (float*)(smem + 38384);
    short* H1T  = (short*)(smem);                 // overlay, phase 3+
    short* H2C  = (short*)(smem + 13312);         // overlay, phase 4+
    float* SCR  = (float*)(smem + 32000);         // overlay, phase 5

    const int b = blockIdx.x, t = threadIdx.x;
    const int w = t >> 6, l = t & 63, lm = l & 15, lq = l >> 4;
    const int nobj = min(maxobj_p[0], O_MAX);

    // ---- phase 0: LBF rows 0-9 from labels, AT2 k-tail zero, theta
    for (int i = t; i < 320; i += 256) {             // 10 rows x 128 c / 4
        float4 v = *(const float4*)&labels[(size_t)b * 1280 + i * 4];
        unsigned lo = f2bf(v.x) | ((unsigned)f2bf(v.y) << 16);
        unsigned hi = f2bf(v.z) | ((unsigned)f2bf(v.w) << 16);
        *(uint2*)&LBF[i * 4] = make_uint2(lo, hi);
    }
    if (t < 192) {                                   // 64 oc x 3 u32 (k 90..96)
        const int oc = t / 3, j = t - oc * 3;
        ((unsigned*)AT2)[oc * 48 + 45 + j] = 0u;
    }
    if (t < 60) TH[t] = theta[b * 60 + t];
    __syncthreads();

    // ---- phase 1a: coverage -> COVf (unpadded, stride-17 rows)
    for (int i = t; i < 2560; i += 256) {
        const int o = i >> 8;
        if (o >= nobj) continue;
        const int p = i & 255, y = p >> 4, x = p & 15;
        const float X = (2.f * x + 1.f) / 16.f - 1.f;
        const float Y = (2.f * y + 1.f) / 16.f - 1.f;
        const float* tt = &TH[o * 6];
        const float gx = tt[0] * X + tt[1] * Y + tt[2];
        const float gy = tt[3] * X + tt[4] * Y + tt[5];
        float ix = (gx + 1.f) * 8.f - 0.5f;
        float x0 = floorf(ix); float fx = ix - x0;
        float inx0 = (x0 >= 0.f  && x0 <= 15.f) ? 1.f : 0.f;
        float inx1 = (x0 >= -1.f && x0 <= 14.f) ? 1.f : 0.f;
        float cx = (1.f - fx) * inx0 + fx * inx1;
        float iy = (gy + 1.f) * 8.f - 0.5f;
        float y0 = floorf(iy); float fy = iy - y0;
        float iny0 = (y0 >= 0.f  && y0 <= 15.f) ? 1.f : 0.f;
        float iny1 = (y0 >= -1.f && y0 <= 14.f) ? 1.f : 0.f;
        float cy = (1.f - fy) * iny0 + fy * iny1;
        COVf[o * 272 + y * 17 + x] = cx * cy;
    }

    // ---- phase 1b: fused A-GEMM.  wave w owns n in [w*144, w*144+144).
    {
        const int n00 = w * 144;
        s8v afr[4];
        #pragma unroll
        for (int ks = 0; ks < 4; ++ks)
            afr[ks] = *(const s8v*)&LBF[lm * 128 + lq * 8 + ks * 32];
        #pragma unroll
        for (int nt = 0; nt < 9; ++nt) {
            const int n = n00 + nt * 16 + lm;
            const short* brow = w1n + (size_t)n * 128 + lq * 8;
            f4v acc = (f4v){0.f, 0.f, 0.f, 0.f};
            #pragma unroll
            for (int ks = 0; ks < 4; ++ks) {
                s8v bb = *(const s8v*)(brow + ks * 32);
                acc = MFMA(afr[ks], bb, acc);
            }
            const int kk = n >> 6, oc = n & 63;
            #pragma unroll
            for (int r = 0; r < 4; ++r) {
                const int m = lq * 4 + r;
                if (m < 10)
                    AT2[oc * 96 + m * 9 + kk] = (short)f2bf(acc[r]);
            }
        }
    }
    __syncthreads();

    // ---- phase 2: covpT[p][k] bf16, all 96 k written (predicate gates OOB)
    for (int i = t; i < 6144; i += 256) {
        const int k = i >> 6, p = i & 63;
        float v = 0.f;
        if (k < 90) {
            const int o  = (k * 456) >> 12;          // k/9
            const int kk = k - 9 * o;
            const int ky = (kk * 11) >> 5, kx = kk - 3 * ky;
            const int y = p >> 3, x = p & 7;
            const int py = 2 * y + ky - 1, px = 2 * x + kx - 1;
            if (o < nobj && (unsigned)py < 16u && (unsigned)px < 16u)
                v = COVf[o * 272 + py * 17 + px];
        }
        CPT[p * 96 + k] = (short)f2bf(v);
    }
    __syncthreads();

    // ---- phase 3: conv1 MFMA.  wave w -> oc tile [16w,16w+16); K=96
    f4v c1[4];
    #pragma unroll
    for (int nt = 0; nt < 4; ++nt) c1[nt] = (f4v){0.f, 0.f, 0.f, 0.f};
    {
        const short* at = AT2 + (16 * w + lm) * 96 + lq * 8;
        const short* cp = CPT + lm * 96 + lq * 8;
        #pragma unroll
        for (int ks = 0; ks < 3; ++ks) {
            s8v a = *(const s8v*)(at + ks * 32);
            #pragma unroll
            for (int nt = 0; nt < 4; ++nt) {
                s8v bb = *(const s8v*)(cp + nt * 1536 + ks * 32);
                c1[nt] = MFMA(a, bb, c1[nt]);
            }
        }
    }
    __syncthreads();   // CPT/AT2 reads done before H1T overlay writes

    // conv1 epilogue: zero H1T border rows, write lrelu(bf16) interior
    for (int i = t; i < 1188; i += 256) {           // 36 border rows x 33 u32
        const int j = i / 33, col = i - 33 * j;
        int r;
        if (j < 10) r = j;
        else if (j < 20) r = 90 + (j - 10);
        else { int jj = j - 20; r = 10 + (jj >> 1) * 10 + ((jj & 1) ? 9 : 0); }
        ((unsigned*)H1T)[r * 33 + col] = 0u;
    }
    #pragma unroll
    for (int nt = 0; nt < 4; ++nt) {
        const int p = nt * 16 + lm, y = p >> 3, x = p & 7;
        const int pix = (y + 1) * 10 + (x + 1);
        #pragma unroll
        for (int r = 0; r < 4; ++r) {
            const int oc = 16 * w + lq * 4 + r;
            float v = c1[nt][r];
            v = (v >= 0.f) ? v : SLOPE * v;
            H1T[pix * 66 + oc] = (short)f2bf(v);
        }
    }
    __syncthreads();

    // ---- phase 4: im2col pairs -> h2colT[p2][k2=tap*64+c] (stride 584)
    for (int i = t; i < 4608; i += 256) {
        const int p2 = i & 15, kp = i >> 4;         // kp = tap*32 + c2
        const int c2 = kp & 31, tap = kp >> 5;
        const int ky = (tap * 11) >> 5, kx = tap - 3 * ky;
        const int y2 = p2 >> 2, x2 = p2 & 3;
        const int pix = (2 * y2 + ky) * 10 + (2 * x2 + kx);
        const unsigned v = *(const unsigned*)&H1T[pix * 66 + 2 * c2];
        *(unsigned*)&H2C[p2 * 584 + tap * 64 + 2 * c2] = v;
    }
    __syncthreads();

    // ---- phase 5: conv2 MFMA. wave: mi = w&1 (oc tile), kh = w>>1 (K half)
    {
        const int mi = w & 1, kh = w >> 1;
        f4v c2 = (f4v){0.f, 0.f, 0.f, 0.f};
        const short* wrow = w2b + (mi * 16 + lm) * 584 + kh * 288 + lq * 8;
        const short* hrow = H2C + lm * 584 + kh * 288 + lq * 8;
        #pragma unroll
        for (int ks = 0; ks < 9; ++ks) {
            s8v a  = *(const s8v*)(wrow + ks * 32);
            s8v bb = *(const s8v*)(hrow + ks * 32);
            c2 = MFMA(a, bb, c2);
        }
        if (kh == 1) *(f4v*)&SCR[(mi * 64 + l) * 4] = c2;
        __syncthreads();
        if (kh == 0) {
            f4v oth = *(const f4v*)&SCR[(mi * 64 + l) * 4];
            #pragma unroll
            for (int r = 0; r < 4; ++r) {
                const int oc = mi * 16 + lq * 4 + r;
                float v = c2[r] + oth[r];
                h2pre[(size_t)b * 512 + oc * 16 + lm] = v;
                float s1 = v, s2 = v * v;
                #pragma unroll
                for (int m = 1; m < 16; m <<= 1) {
                    s1 += __shfl_xor(s1, m, 16);
                    s2 += __shfl_xor(s2, m, 16);
                }
                if (lm == 0) { CS[oc] = s1; CS2[oc] = s2; }
            }
        }
    }
    __syncthreads();
    if (t < 32) {
        atomicAdd(&bn2s[t],  CS[t]);
        atomicAdd(&bn2s2[t], CS2[t]);
    }
}

// ---------------------------------------------------------------------------
// stage2 (8 b per block, 256 blocks): identical to R6
// ---------------------------------------------------------------------------
__global__ __launch_bounds__(256) void stage2(
    const float* __restrict__ h2pre,
    const float* __restrict__ gamma2, const float* __restrict__ beta2,
    const short* __restrict__ w3b,    // (16,288) bf16, k2=tap*32+c
    const float* __restrict__ bn2s, const float* __restrict__ bn2s2,
    float* __restrict__ h3pre,        // (B,16,2,2)
    float* __restrict__ bn3s, float* __restrict__ bn3s2, int B)
{
    const int b0 = blockIdx.x * 8, t = threadIdx.x;
    const int w = t >> 6, l = t & 63, lm = l & 15, lq = l >> 4;
    __shared__ float s_ss[64];                      // scale[32] | shift[32]
    __shared__ short s_h2a[8 * 512];                // [lb][c][p] bf16
    __shared__ __align__(16) short h3c[32 * 296];   // [n=(lb,p)][k2]

    if (t < 32) {
        const float n = (float)B * 16.f;
        const float mean = bn2s[t] / n;
        const float var  = bn2s2[t] / n - mean * mean;
        const float sc   = gamma2[t] * rsqrtf(var + BN_EPS);
        s_ss[t] = sc;
        s_ss[32 + t] = beta2[t] - mean * sc;
    }
    __syncthreads();

    for (int i = t; i < 4096; i += 256) {
        const int c = (i >> 4) & 31;
        const float v = h2pre[(size_t)b0 * 512 + i] * s_ss[c] + s_ss[32 + c];
        s_h2a[i] = (short)f2bf((v >= 0.f) ? v : SLOPE * v);
    }
    __syncthreads();

    for (int i = t; i < 9216; i += 256) {
        const int n = i & 31, k2 = i >> 5;
        const int c = k2 & 31, tap = k2 >> 5;
        const int ky = (tap * 11) >> 5, kx = tap - 3 * ky;
        const int lb = n >> 2, p = n & 3, y = p >> 1, x = p & 1;
        const int iy = 2 * y + ky - 1, ix = 2 * x + kx - 1;
        short v = 0;
        if ((unsigned)iy < 4u && (unsigned)ix < 4u)
            v = s_h2a[lb * 512 + c * 16 + iy * 4 + ix];
        h3c[n * 296 + k2] = v;
    }
    __syncthreads();

    if (w < 2) {            // wave w handles n rows [16w, 16w+16)
        f4v acc = (f4v){0.f, 0.f, 0.f, 0.f};
        const short* wr = w3b + lm * 288 + lq * 8;
        const short* hr = h3c + (w * 16 + lm) * 296 + lq * 8;
        #pragma unroll
        for (int ks = 0; ks < 9; ++ks) {
            s8v a  = *(const s8v*)(wr + ks * 32);
            s8v bb = *(const s8v*)(hr + ks * 32);
            acc = MFMA(a, bb, acc);
        }
        const int n = w * 16 + lm, lb = n >> 2, p = n & 3;
        #pragma unroll
        for (int r = 0; r < 4; ++r) {
            const int oc = lq * 4 + r;
            const float v = acc[r];
            h3pre[(size_t)(b0 + lb) * 64 + oc * 4 + p] = v;
            float s1 = v, s2 = v * v;
            #pragma unroll
            for (int m = 1; m < 16; m <<= 1) {
                s1 += __shfl_xor(s1, m, 16);
                s2 += __shfl_xor(s2, m, 16);
            }
            if (lm == 0) {
                atomicAdd(&bn3s[oc],  s1);
                atomicAdd(&bn3s2[oc], s2);
            }
        }
    }
}

// ---------------------------------------------------------------------------
// stage3: BN3 + lrelu -> out (B,64)   (identical to R6)
// ---------------------------------------------------------------------------
__global__ __launch_bounds__(256) void stage3(
    const float* __restrict__ h3pre,
    const float* __restrict__ gamma3, const float* __restrict__ beta3,
    const float* __restrict__ bn3s, const float* __restrict__ bn3s2,
    float* __restrict__ out, int total, int B)
{
    __shared__ float s_scale[16], s_shift[16];
    if (threadIdx.x < 16) {
        const int c = threadIdx.x;
        const float n = (float)B * 4.f;
        const float mean = bn3s[c] / n;
        const float var  = bn3s2[c] / n - mean * mean;
        const float sc   = gamma3[c] * rsqrtf(var + BN_EPS);
        s_scale[c] = sc;
        s_shift[c] = beta3[c] - mean * sc;
    }
    __syncthreads();
    const int idx = blockIdx.x * 256 + threadIdx.x;
    if (idx < total) {
        const int c = (idx & 63) >> 2;
        const float v = h3pre[idx] * s_scale[c] + s_shift[c];
        out[idx] = (v >= 0.f) ? v : SLOPE * v;
    }
}

extern "C" void kernel_launch(void* const* d_in, const int* in_sizes, int n_in,
                              void* d_out, int out_size, void* d_ws, size_t ws_size,
                              hipStream_t stream)
{
    const float* labels = (const float*)d_in[0];
    const float* theta  = (const float*)d_in[1];
    const float* w1     = (const float*)d_in[2];
    const float* w2     = (const float*)d_in[3];
    const float* gamma2 = (const float*)d_in[4];
    const float* beta2  = (const float*)d_in[5];
    const float* w3     = (const float*)d_in[6];
    const float* gamma3 = (const float*)d_in[7];
    const float* beta3  = (const float*)d_in[8];
    const int*   maxobj = (const int*)d_in[9];

    const int B = in_sizes[0] / (O_MAX * C_DIM);   // 2048

    unsigned char* ws = (unsigned char*)d_ws;
    float* h2pre = (float*)ws;                                  // B*512 f32
    float* h3pre = h2pre + (size_t)B * 512;                     // B*64
    float* sums  = h3pre + (size_t)B * 64;                      // 96
    short* w1n   = (short*)(sums + 96);                         // 73728 sh
    short* w2b   = w1n + N_W1N;                                 // 18688 sh
    short* w3b   = w2b + N_W2B;                                 // 4608 sh
    float* bn2s  = sums;
    float* bn2s2 = sums + 32;
    float* bn3s  = sums + 64;
    float* bn3s2 = sums + 80;

    const int prep_total = N_W1N + N_W2B + N_W3B + 96;
    prep<<<(prep_total + 255) / 256, 256, 0, stream>>>(w1, w2, w3,
                                                       w1n, w2b, w3b, sums);
    stage1<<<B, 256, 0, stream>>>(labels, theta, w1n, w2b, maxobj,
                                  h2pre, bn2s, bn2s2);
    stage2<<<B / 8, 256, 0, stream>>>(h2pre, gamma2, beta2, w3b, bn2s, bn2s2,
                                      h3pre, bn3s, bn3s2, B);
    const int total = B * 64;
    stage3<<<(total + 255) / 256, 256, 0, stream>>>(h3pre, gamma3, beta3,
                                                    bn3s, bn3s2, (float*)d_out,
                                                    total, B);
}